// Round 4
// baseline (318.412 us; speedup 1.0000x reference)
//
#include <hip/hip_runtime.h>
#include <hip/hip_bf16.h>

#define B_ 16384
#define NF_ 16
#define VOCAB_ 100000
#define ED_ 32
#define NNUM_ 13
#define E_ 8
#define T_ 2
#define H0_ 512
#define H1_ 256
#define TH_ 128
#define D0_ 525
#define K0P 576   // padded K for layer 0 (multiple of 64)

// 256x256 tile, BK=64, 8 waves (2Mx4N), double-buffered LDS, counted vmcnt
#define GBM 256
#define GBN 256

typedef __bf16 bf16x8 __attribute__((ext_vector_type(8)));
typedef float  f32x4  __attribute__((ext_vector_type(4)));
typedef int    i32x4  __attribute__((ext_vector_type(4)));

typedef __attribute__((address_space(3))) void lds_void;
typedef __attribute__((address_space(1))) const void gbl_void;

__device__ __forceinline__ void load_lds16f(const void* g, void* l) {
  __builtin_amdgcn_global_load_lds((gbl_void*)g, (lds_void*)l, 16, 0, 0);
}

// ---------------- embedding + concat + pad + cast ----------------
__global__ __launch_bounds__(192) void k_embed(const int* __restrict__ cat,
                                               const float* __restrict__ num,
                                               const float* __restrict__ emb,
                                               __hip_bfloat16* __restrict__ x) {
  int b = blockIdx.x;
  int t = threadIdx.x;
  const int* crow = cat + b * NF_;
#pragma unroll
  for (int i = 0; i < 3; ++i) {
    int d = t + i * 192;  // 0..575
    float v;
    if (d < 512) {
      int f = d >> 5, c = d & 31;
      v = emb[((long long)(f * VOCAB_ + crow[f])) * ED_ + c];
    } else if (d < D0_) {
      v = num[b * NNUM_ + (d - 512)];
    } else {
      v = 0.f;
    }
    x[(long long)b * K0P + d] = __float2bfloat16(v);
  }
}

// ---------------- weight transpose + pad + cast: W[E][K][N] f32 -> Wp[E][N][KP] bf16 ----------------
__global__ __launch_bounds__(256) void k_wprep(const float* __restrict__ W,
                                               __hip_bfloat16* __restrict__ Wp,
                                               int K, int N, int KP) {
  __shared__ float tile[64][65];
  int k0 = blockIdx.x * 64, n0 = blockIdx.y * 64, e = blockIdx.z;
  int tx = threadIdx.x & 63, ty = threadIdx.x >> 6;
  for (int r = ty; r < 64; r += 4) {
    int k = k0 + r;
    tile[r][tx] = (k < K) ? W[((long long)e * K + k) * N + n0 + tx] : 0.f;
  }
  __syncthreads();
  for (int r = ty; r < 64; r += 4) {
    int n = n0 + r;
    Wp[((long long)e * N + n) * KP + k0 + tx] = __float2bfloat16(tile[tx][r]);
  }
}

// ---------------- BN param folding ----------------
__global__ void k_prep_small(const float* b0, const float* g0, const float* be0,
                             const float* m0, const float* v0,
                             const float* b1, const float* g1, const float* be1,
                             const float* m1, const float* v1,
                             const float* bt1, const float* tg, const float* tb,
                             const float* tm, const float* tv,
                             float* scale0, float* ebias0, float* scale1, float* ebias1,
                             float* tscale, float* tbias) {
  int i = blockIdx.x * 256 + threadIdx.x;
  if (i < H0_) scale0[i] = g0[i] * rsqrtf(v0[i] + 1e-5f);
  if (i < H1_) scale1[i] = g1[i] * rsqrtf(v1[i] + 1e-5f);
  if (i < T_ * TH_) {
    float s = tg[i] * rsqrtf(tv[i] + 1e-5f);
    tscale[i] = s;
    tbias[i] = (bt1[i] - tm[i]) * s + tb[i];
  }
  if (i < E_ * H0_) {
    int n = i & (H0_ - 1);
    float s = g0[n] * rsqrtf(v0[n] + 1e-5f);
    ebias0[i] = (b0[i] - m0[n]) * s + be0[n];
  }
  if (i < E_ * H1_) {
    int n = i & (H1_ - 1);
    float s = g1[n] * rsqrtf(v1[n] + 1e-5f);
    ebias1[i] = (b1[i] - m1[n]) * s + be1[n];
  }
}

// ---------------- gate logits + softmax over 8 experts ----------------
__global__ __launch_bounds__(256) void k_gates(const __hip_bfloat16* __restrict__ x,
                                               const float* __restrict__ Wg,
                                               const float* __restrict__ bg,
                                               float* __restrict__ gates) {
  int gidx = blockIdx.x * 256 + threadIdx.x;
  int b = gidx >> 4, te = gidx & 15;
  int t = te >> 3, e = te & 7;
  const __hip_bfloat16* xr = x + (long long)b * K0P;
  const float* wg = Wg + ((long long)t * D0_) * E_ + e;
  float acc = bg[t * E_ + e];
  int k = 0;
  for (; k + 8 <= D0_; k += 8) {
    bf16x8 xv = *reinterpret_cast<const bf16x8*>(xr + k);
#pragma unroll
    for (int j = 0; j < 8; ++j)
      acc += (float)xv[j] * wg[(long long)(k + j) * E_];
  }
  for (; k < D0_; ++k) acc += __bfloat162float(xr[k]) * wg[(long long)k * E_];
  float mx = acc;
#pragma unroll
  for (int o = 1; o < 8; o <<= 1) mx = fmaxf(mx, __shfl_xor(mx, o));
  float p = __expf(acc - mx);
  float s = p;
#pragma unroll
  for (int o = 1; o < 8; o <<= 1) s += __shfl_xor(s, o);
  gates[((long long)t * B_ + b) * E_ + e] = p / s;
}

// ---------------- grouped GEMM + BN + ReLU -> bf16 ----------------
// 256x256 tile, 8 waves, double-buffered gl_lds staging with counted vmcnt.
// A: [e?][M][lda] bf16 row-major.  Bw: [e][N][ldb] bf16 (output-feature-major).
// C[e][M][N] = relu( (A @ Bw^T) * scale[n] + ebias[e][n] )
// LDS[r][c] = G[r][c ^ ((r&7)<<4)] via pre-swizzled source; same XOR on read.
__global__ __launch_bounds__(512, 2) void k_gemm(
    const __hip_bfloat16* __restrict__ Aall, long long strideAe, int lda,
    const __hip_bfloat16* __restrict__ Ball, long long strideBe, int ldb,
    __hip_bfloat16* __restrict__ Call, long long strideCe, int N,
    const float* __restrict__ scale, const float* __restrict__ ebias, int strideEb,
    int K) {
  __shared__ __align__(16) char As[2][32768];  // 256 rows x 128 B per slot
  __shared__ __align__(16) char Bs[2][32768];

  const int e = blockIdx.z;
  const char* A = reinterpret_cast<const char*>(Aall + (long long)e * strideAe +
                                                (long long)blockIdx.x * GBM * lda);
  const char* Bw = reinterpret_cast<const char*>(Ball + (long long)e * strideBe +
                                                 (long long)blockIdx.y * GBN * ldb);
  const int ldab = lda * 2, ldbb = ldb * 2;

  const int tid = threadIdx.x;
  const int lane = tid & 63;
  const int wid = tid >> 6;
  const int wr = wid >> 2, wc = wid & 3;  // wave tile: rows wr*128.., cols wc*64..

  // staging: call i covers rows [i*64, i*64+64); thread t -> row i*64+(t>>3),
  // chunk (t&7)*16. LDS dest linear = i*8192 + t*16 (wave-uniform base + lane*16).
  const int stg_row = tid >> 3;
  const int swz = ((tid & 7) << 4) ^ ((stg_row & 7) << 4);

  f32x4 acc[8][4];
#pragma unroll
  for (int m = 0; m < 8; ++m)
#pragma unroll
    for (int n = 0; n < 4; ++n) acc[m][n] = (f32x4){0.f, 0.f, 0.f, 0.f};

  const int nk = K / 64;

#define STAGE_TILE(kt_, s_)                                                     \
  do {                                                                          \
    const long long kb0_ = (long long)(kt_) * 128;                              \
    char* adst_ = As[(s_)] + tid * 16;                                          \
    char* bdst_ = Bs[(s_)] + tid * 16;                                          \
    _Pragma("unroll")                                                           \
    for (int i_ = 0; i_ < 4; ++i_) {                                            \
      const int row_ = stg_row + i_ * 64;                                       \
      load_lds16f(A + (long long)row_ * ldab + kb0_ + swz, adst_ + i_ * 8192);  \
      load_lds16f(Bw + (long long)row_ * ldbb + kb0_ + swz, bdst_ + i_ * 8192); \
    }                                                                           \
  } while (0)

  // prologue: stage tile 0 into slot 0
  STAGE_TILE(0, 0);

  for (int kt = 0; kt < nk; ++kt) {
    const int cur = kt & 1;
    if (kt + 1 < nk) {
      STAGE_TILE(kt + 1, cur ^ 1);
      asm volatile("s_waitcnt vmcnt(8)" ::: "memory");  // tile kt landed; kt+1 in flight
    } else {
      asm volatile("s_waitcnt vmcnt(0)" ::: "memory");
    }
    __builtin_amdgcn_s_barrier();

    const char* Ab = As[cur];
    const char* Bb = Bs[cur];
#pragma unroll
    for (int mh = 0; mh < 2; ++mh)
#pragma unroll
      for (int nh = 0; nh < 2; ++nh) {
        bf16x8 af[2][4], bq[2][2];
#pragma unroll
        for (int kk = 0; kk < 2; ++kk) {
          const int kb = kk * 64 + (lane >> 4) * 16;
#pragma unroll
          for (int m = 0; m < 4; ++m) {
            const int row = wr * 128 + (mh * 4 + m) * 16 + (lane & 15);
            af[kk][m] = *reinterpret_cast<const bf16x8*>(
                Ab + row * 128 + (kb ^ ((row & 7) << 4)));
          }
#pragma unroll
          for (int n = 0; n < 2; ++n) {
            const int row = wc * 64 + (nh * 2 + n) * 16 + (lane & 15);
            bq[kk][n] = *reinterpret_cast<const bf16x8*>(
                Bb + row * 128 + (kb ^ ((row & 7) << 4)));
          }
        }
        __builtin_amdgcn_s_setprio(1);
#pragma unroll
        for (int kk = 0; kk < 2; ++kk)
#pragma unroll
          for (int m = 0; m < 4; ++m)
#pragma unroll
            for (int n = 0; n < 2; ++n)
              acc[mh * 4 + m][nh * 2 + n] = __builtin_amdgcn_mfma_f32_16x16x32_bf16(
                  af[kk][m], bq[kk][n], acc[mh * 4 + m][nh * 2 + n], 0, 0, 0);
        __builtin_amdgcn_s_setprio(0);
      }
    asm volatile("" ::: "memory");
    __builtin_amdgcn_s_barrier();  // reads of slot cur done -> safe to overwrite next iter
  }
#undef STAGE_TILE

  __hip_bfloat16* C = Call + (long long)e * strideCe;
  const float* eb = ebias + e * strideEb;
  const int m0 = blockIdx.x * GBM, n0 = blockIdx.y * GBN;
#pragma unroll
  for (int n = 0; n < 4; ++n) {
    int col = n0 + wc * 64 + n * 16 + (lane & 15);
    float s = scale[col];
    float bb = eb[col];
#pragma unroll
    for (int m = 0; m < 8; ++m) {
      int rowb = m0 + wr * 128 + m * 16 + (lane >> 4) * 4;
#pragma unroll
      for (int i = 0; i < 4; ++i) {
        float v = fmaxf(acc[m][n][i] * s + bb, 0.f);
        C[(long long)(rowb + i) * N + col] = __float2bfloat16(v);
      }
    }
  }
}

// ---------------- fused combine + BOTH tower MLPs + sigmoid ----------------
// grid: (B/64), block 256 (4 waves, each wave owns 16 rows). h1 read ONCE for both tasks.
__global__ __launch_bounds__(256) void k_tower(
    const __hip_bfloat16* __restrict__ h1, const float* __restrict__ gates,
    const float* __restrict__ Wt1, const float* __restrict__ Wt2,
    const float* __restrict__ bt2, const float* __restrict__ tscale,
    const float* __restrict__ tbias, float* __restrict__ out) {
  __shared__ __align__(16) char Ws[TH_ * 512];  // Ws[h][k] bf16, swizzled; one task at a time
  const int tid = threadIdx.x;
  const int lane = tid & 63, wv = tid >> 6;

  const int row = blockIdx.x * 64 + wv * 16 + (lane & 15);
  const int g4 = lane >> 4;

  float gt0[8], gt1[8];
  {
    const float* gp0 = gates + (long long)row * E_;
    const float* gp1 = gates + ((long long)B_ + row) * E_;
#pragma unroll
    for (int j = 0; j < 8; ++j) { gt0[j] = gp0[j]; gt1[j] = gp1[j]; }
  }

  // combine both tasks from one h1 stream:
  // fea[t][row][k], k = c*32 + g4*8 + j  (A-fragment slots)
  float fa0[8][8], fa1[8][8];
#pragma unroll
  for (int c = 0; c < 8; ++c)
#pragma unroll
    for (int j = 0; j < 8; ++j) { fa0[c][j] = 0.f; fa1[c][j] = 0.f; }

#pragma unroll
  for (int ee = 0; ee < 8; ++ee) {
    const char* hp = reinterpret_cast<const char*>(h1) +
                     (((long long)ee * B_ + row) * H1_ + g4 * 8) * 2;
    float ga = gt0[ee], gb = gt1[ee];
#pragma unroll
    for (int c = 0; c < 8; ++c) {
      bf16x8 hv = *reinterpret_cast<const bf16x8*>(hp + c * 64);
#pragma unroll
      for (int j = 0; j < 8; ++j) {
        float v = (float)hv[j];
        fa0[c][j] += ga * v;
        fa1[c][j] += gb * v;
      }
    }
  }
  bf16x8 af0[8], af1[8];
#pragma unroll
  for (int c = 0; c < 8; ++c)
#pragma unroll
    for (int j = 0; j < 8; ++j) {
      af0[c][j] = (__bf16)fa0[c][j];
      af1[c][j] = (__bf16)fa1[c][j];
    }

#pragma unroll
  for (int t = 0; t < T_; ++t) {
    if (t) __syncthreads();  // all reads of Ws for previous task done
    // stage Wt1[t][k][h] f32 -> Ws[h][k] bf16 (swizzled); coalesced over h
    for (int it = 0; it < 16; ++it) {
      int idx = it * 256 + tid;
      int h = idx & 127, kc = idx >> 7;  // kc in 0..31 (chunks of 8 k)
      bf16x8 v;
#pragma unroll
      for (int j = 0; j < 8; ++j)
        v[j] = (__bf16)Wt1[((long long)t * H1_ + kc * 8 + j) * TH_ + h];
      int byt = h * 512 + ((kc * 16) ^ ((h & 7) << 4));
      *reinterpret_cast<bf16x8*>(Ws + byt) = v;
    }
    __syncthreads();

    f32x4 acc[8];
#pragma unroll
    for (int n = 0; n < 8; ++n) acc[n] = (f32x4){0.f, 0.f, 0.f, 0.f};
#pragma unroll
    for (int c = 0; c < 8; ++c) {
      int kb = c * 64 + g4 * 16;
#pragma unroll
      for (int n = 0; n < 8; ++n) {
        int hrow = n * 16 + (lane & 15);
        bf16x8 bv = *reinterpret_cast<const bf16x8*>(Ws + hrow * 512 + (kb ^ ((hrow & 7) << 4)));
        acc[n] = __builtin_amdgcn_mfma_f32_16x16x32_bf16(t ? af1[c] : af0[c], bv, acc[n], 0, 0, 0);
      }
    }

    float part[4] = {0.f, 0.f, 0.f, 0.f};
#pragma unroll
    for (int n = 0; n < 8; ++n) {
      int col = n * 16 + (lane & 15);
      float s = tscale[t * TH_ + col], bb = tbias[t * TH_ + col], w2 = Wt2[t * TH_ + col];
#pragma unroll
      for (int i = 0; i < 4; ++i)
        part[i] += fmaxf(acc[n][i] * s + bb, 0.f) * w2;
    }
#pragma unroll
    for (int o = 1; o < 16; o <<= 1) {
#pragma unroll
      for (int i = 0; i < 4; ++i) part[i] += __shfl_xor(part[i], o);
    }
    if ((lane & 15) == 0) {
      int rbase = blockIdx.x * 64 + wv * 16 + g4 * 4;
      float b2 = bt2[t];
#pragma unroll
      for (int i = 0; i < 4; ++i) {
        float z = part[i] + b2;
        out[(long long)t * B_ + rbase + i] = 1.f / (1.f + __expf(-z));
      }
    }
  }
}

extern "C" void kernel_launch(void* const* d_in, const int* in_sizes, int n_in,
                              void* d_out, int out_size, void* d_ws, size_t ws_size,
                              hipStream_t stream) {
  const int*   cat = (const int*)d_in[0];
  const float* num = (const float*)d_in[1];
  const float* emb = (const float*)d_in[3];
  const float* W0  = (const float*)d_in[4];
  const float* b0  = (const float*)d_in[5];
  const float* g0  = (const float*)d_in[6];
  const float* be0 = (const float*)d_in[7];
  const float* m0  = (const float*)d_in[8];
  const float* v0  = (const float*)d_in[9];
  const float* W1  = (const float*)d_in[10];
  const float* b1  = (const float*)d_in[11];
  const float* g1  = (const float*)d_in[12];
  const float* be1 = (const float*)d_in[13];
  const float* m1  = (const float*)d_in[14];
  const float* v1  = (const float*)d_in[15];
  const float* Wg  = (const float*)d_in[16];
  const float* bg  = (const float*)d_in[17];
  const float* Wt1 = (const float*)d_in[18];
  const float* bt1 = (const float*)d_in[19];
  const float* tg  = (const float*)d_in[20];
  const float* tb  = (const float*)d_in[21];
  const float* tm  = (const float*)d_in[22];
  const float* tv  = (const float*)d_in[23];
  const float* Wt2 = (const float*)d_in[24];
  const float* bt2 = (const float*)d_in[25];
  float* out = (float*)d_out;

  char* ws = (char*)d_ws;
  if (ws_size < 228094976ULL) return;  // layout below needs ~228 MB

  __hip_bfloat16* x_bf = (__hip_bfloat16*)(ws + 0ULL);           // 16384*576*2
  __hip_bfloat16* W0p  = (__hip_bfloat16*)(ws + 18874368ULL);    // 8*512*576*2
  __hip_bfloat16* W1p  = (__hip_bfloat16*)(ws + 23592960ULL);    // 8*256*512*2
  float* gates   = (float*)(ws + 25690112ULL);                   // 2*16384*8*4
  float* scale0  = (float*)(ws + 26738688ULL);
  float* ebias0  = (float*)(ws + 26740736ULL);
  float* scale1  = (float*)(ws + 26757120ULL);
  float* ebias1  = (float*)(ws + 26758144ULL);
  float* tscale  = (float*)(ws + 26766336ULL);
  float* tbias   = (float*)(ws + 26767360ULL);
  __hip_bfloat16* h0 = (__hip_bfloat16*)(ws + 26768384ULL);      // 8*16384*512*2
  __hip_bfloat16* h1 = (__hip_bfloat16*)(ws + 160986112ULL);     // 8*16384*256*2

  // weight prep + BN folding
  k_wprep<<<dim3(K0P / 64, H0_ / 64, E_), 256, 0, stream>>>(W0, W0p, D0_, H0_, K0P);
  k_wprep<<<dim3(H0_ / 64, H1_ / 64, E_), 256, 0, stream>>>(W1, W1p, H0_, H1_, H0_);
  k_prep_small<<<16, 256, 0, stream>>>(b0, g0, be0, m0, v0, b1, g1, be1, m1, v1,
                                       bt1, tg, tb, tm, tv,
                                       scale0, ebias0, scale1, ebias1, tscale, tbias);
  // embedding + concat
  k_embed<<<B_, 192, 0, stream>>>(cat, num, emb, x_bf);
  // gates
  k_gates<<<B_ * 16 / 256, 256, 0, stream>>>(x_bf, Wg, bg, gates);
  // layer 0: [B,576] x [E,512,576]^T -> h0 [E,B,512]
  k_gemm<<<dim3(B_ / GBM, H0_ / GBN, E_), 512, 0, stream>>>(
      x_bf, 0LL, K0P, W0p, (long long)H0_ * K0P, K0P,
      h0, (long long)B_ * H0_, H0_, scale0, ebias0, H0_, K0P);
  // layer 1: h0 [E,B,512] x [E,256,512]^T -> h1 [E,B,256]
  k_gemm<<<dim3(B_ / GBM, H1_ / GBN, E_), 512, 0, stream>>>(
      h0, (long long)B_ * H0_, H0_, W1p, (long long)H1_ * H0_, H0_,
      h1, (long long)B_ * H1_, H1_, scale1, ebias1, H1_, H0_);
  // combine + BOTH towers + sigmoid
  k_tower<<<dim3(B_ / 64), 256, 0, stream>>>(h1, gates, Wt1, Wt2, bt2,
                                             tscale, tbias, out);
}

// Round 5
// 294.937 us; speedup vs baseline: 1.0796x; 1.0796x over previous
//
#include <hip/hip_runtime.h>
#include <hip/hip_bf16.h>

#define B_ 16384
#define NF_ 16
#define VOCAB_ 100000
#define ED_ 32
#define NNUM_ 13
#define E_ 8
#define T_ 2
#define H0_ 512
#define H1_ 256
#define TH_ 128
#define D0_ 525
#define K0P 640   // padded K for layer 0 (multiple of 128 -> even # of 64-K-tiles)

typedef __bf16 bf16x8 __attribute__((ext_vector_type(8)));
typedef float  f32x4  __attribute__((ext_vector_type(4)));

typedef __attribute__((address_space(3))) void lds_void;
typedef __attribute__((address_space(1))) const void gbl_void;

__device__ __forceinline__ void load_lds16f(const void* g, void* l) {
  __builtin_amdgcn_global_load_lds((gbl_void*)g, (lds_void*)l, 16, 0, 0);
}

#define BARX                                        \
  do {                                              \
    asm volatile("" ::: "memory");                  \
    __builtin_amdgcn_s_barrier();                   \
    __builtin_amdgcn_sched_barrier(0);              \
    asm volatile("" ::: "memory");                  \
  } while (0)
#define LGKM0                                       \
  do {                                              \
    asm volatile("s_waitcnt lgkmcnt(0)" ::: "memory"); \
    __builtin_amdgcn_sched_barrier(0);              \
  } while (0)

// ---------------- embedding + concat + pad + cast ----------------
__global__ __launch_bounds__(256) void k_embed(const int* __restrict__ cat,
                                               const float* __restrict__ num,
                                               const float* __restrict__ emb,
                                               __hip_bfloat16* __restrict__ x) {
  int b = blockIdx.x;
  int t = threadIdx.x;
  const int* crow = cat + b * NF_;
#pragma unroll
  for (int i = 0; i < 3; ++i) {
    int d = t + i * 256;  // 0..767
    if (d >= K0P) continue;
    float v;
    if (d < 512) {
      int f = d >> 5, c = d & 31;
      v = emb[((long long)(f * VOCAB_ + crow[f])) * ED_ + c];
    } else if (d < D0_) {
      v = num[b * NNUM_ + (d - 512)];
    } else {
      v = 0.f;
    }
    x[(long long)b * K0P + d] = __float2bfloat16(v);
  }
}

// ---------------- weight transpose + pad + cast: W[E][K][N] f32 -> Wp[E][N][KP] bf16 ----------------
__global__ __launch_bounds__(256) void k_wprep(const float* __restrict__ W,
                                               __hip_bfloat16* __restrict__ Wp,
                                               int K, int N, int KP) {
  __shared__ float tile[64][65];
  int k0 = blockIdx.x * 64, n0 = blockIdx.y * 64, e = blockIdx.z;
  int tx = threadIdx.x & 63, ty = threadIdx.x >> 6;
  for (int r = ty; r < 64; r += 4) {
    int k = k0 + r;
    tile[r][tx] = (k < K) ? W[((long long)e * K + k) * N + n0 + tx] : 0.f;
  }
  __syncthreads();
  for (int r = ty; r < 64; r += 4) {
    int n = n0 + r;
    Wp[((long long)e * N + n) * KP + k0 + tx] = __float2bfloat16(tile[tx][r]);
  }
}

// ---------------- BN param folding ----------------
__global__ void k_prep_small(const float* b0, const float* g0, const float* be0,
                             const float* m0, const float* v0,
                             const float* b1, const float* g1, const float* be1,
                             const float* m1, const float* v1,
                             const float* bt1, const float* tg, const float* tb,
                             const float* tm, const float* tv,
                             float* scale0, float* ebias0, float* scale1, float* ebias1,
                             float* tscale, float* tbias) {
  int i = blockIdx.x * 256 + threadIdx.x;
  if (i < H0_) scale0[i] = g0[i] * rsqrtf(v0[i] + 1e-5f);
  if (i < H1_) scale1[i] = g1[i] * rsqrtf(v1[i] + 1e-5f);
  if (i < T_ * TH_) {
    float s = tg[i] * rsqrtf(tv[i] + 1e-5f);
    tscale[i] = s;
    tbias[i] = (bt1[i] - tm[i]) * s + tb[i];
  }
  if (i < E_ * H0_) {
    int n = i & (H0_ - 1);
    float s = g0[n] * rsqrtf(v0[n] + 1e-5f);
    ebias0[i] = (b0[i] - m0[n]) * s + be0[n];
  }
  if (i < E_ * H1_) {
    int n = i & (H1_ - 1);
    float s = g1[n] * rsqrtf(v1[n] + 1e-5f);
    ebias1[i] = (b1[i] - m1[n]) * s + be1[n];
  }
}

// ---------------- gate logits + softmax over 8 experts ----------------
__global__ __launch_bounds__(256) void k_gates(const __hip_bfloat16* __restrict__ x,
                                               const float* __restrict__ Wg,
                                               const float* __restrict__ bg,
                                               float* __restrict__ gates) {
  int gidx = blockIdx.x * 256 + threadIdx.x;
  int b = gidx >> 4, te = gidx & 15;
  int t = te >> 3, e = te & 7;
  const __hip_bfloat16* xr = x + (long long)b * K0P;
  const float* wg = Wg + ((long long)t * D0_) * E_ + e;
  float acc = bg[t * E_ + e];
  int k = 0;
  for (; k + 8 <= D0_; k += 8) {
    bf16x8 xv = *reinterpret_cast<const bf16x8*>(xr + k);
#pragma unroll
    for (int j = 0; j < 8; ++j)
      acc += (float)xv[j] * wg[(long long)(k + j) * E_];
  }
  for (; k < D0_; ++k) acc += __bfloat162float(xr[k]) * wg[(long long)k * E_];
  float mx = acc;
#pragma unroll
  for (int o = 1; o < 8; o <<= 1) mx = fmaxf(mx, __shfl_xor(mx, o));
  float p = __expf(acc - mx);
  float s = p;
#pragma unroll
  for (int o = 1; o < 8; o <<= 1) s += __shfl_xor(s, o);
  gates[((long long)t * B_ + b) * E_ + e] = p / s;
}

// ---------------- grouped GEMM + BN + ReLU -> bf16, 8-phase schedule ----------------
// 256x256 tile, BK=64, 8 waves. Per-phase: block-level 128x128 C-quadrant (Qm,Qn);
// wave (wq_r, wq_c) owns 64x32 of it. Quadrant order (0,0),(0,1),(1,1),(1,0) ->
// A-frags held 2 phases, B-frags held 2 phases (28 ds_read_b128 / wave / K-tile).
// Half-tile staging staggered so each gl_lds targets a region whose reads closed.
// vmcnt(4) only at phases 4 and 8 (2 half-tiles always in flight).
__global__ __launch_bounds__(512, 2) void k_gemm(
    const __hip_bfloat16* __restrict__ Aall, long long strideAe, int lda,
    const __hip_bfloat16* __restrict__ Ball, long long strideBe, int ldb,
    __hip_bfloat16* __restrict__ Call, long long strideCe, int N,
    const float* __restrict__ scale, const float* __restrict__ ebias, int strideEb,
    int K) {
  __shared__ __align__(16) char As[2][2][16384];  // [slot][half]: 128 rows x 128 B
  __shared__ __align__(16) char Bs[2][2][16384];

  const int e = blockIdx.z;
  const char* A = reinterpret_cast<const char*>(Aall + (long long)e * strideAe +
                                                (long long)blockIdx.x * 256 * lda);
  const char* Bw = reinterpret_cast<const char*>(Ball + (long long)e * strideBe +
                                                 (long long)blockIdx.y * 256 * ldb);
  const int ldab = lda * 2, ldbb = ldb * 2;

  const int tid = threadIdx.x;
  const int lane = tid & 63;
  const int wid = tid >> 6;
  const int wq_r = wid >> 2, wq_c = wid & 3;  // within-quadrant: 2Mx4N waves

  const int srow = tid >> 3;                          // 0..63
  const int swz = ((tid & 7) << 4) ^ ((srow & 7) << 4);

  // stage half-tile (2 gl_lds/thread): mat half `half` of K-tile kt into slot
  auto STG_A = [&](int kt, int half, int slot) {
#pragma unroll
    for (int j = 0; j < 2; ++j) {
      const int lrow = srow + j * 64;
      load_lds16f(A + (long long)(half * 128 + lrow) * ldab + kt * 128 + swz,
                  &As[slot][half][j * 8192 + tid * 16]);
    }
  };
  auto STG_B = [&](int kt, int half, int slot) {
#pragma unroll
    for (int j = 0; j < 2; ++j) {
      const int lrow = srow + j * 64;
      load_lds16f(Bw + (long long)(half * 128 + lrow) * ldbb + kt * 128 + swz,
                  &Bs[slot][half][j * 8192 + tid * 16]);
    }
  };

  bf16x8 af[2][4], bq[2][2];
  auto LDA = [&](int slot, int half) {
#pragma unroll
    for (int kk = 0; kk < 2; ++kk) {
      const int kb = kk * 64 + (lane >> 4) * 16;
#pragma unroll
      for (int m = 0; m < 4; ++m) {
        const int lrow = wq_r * 64 + m * 16 + (lane & 15);
        af[kk][m] = *reinterpret_cast<const bf16x8*>(
            &As[slot][half][lrow * 128 + (kb ^ ((lane & 7) << 4))]);
      }
    }
  };
  auto LDB = [&](int slot, int half) {
#pragma unroll
    for (int kk = 0; kk < 2; ++kk) {
      const int kb = kk * 64 + (lane >> 4) * 16;
#pragma unroll
      for (int n = 0; n < 2; ++n) {
        const int lrow = wq_c * 32 + n * 16 + (lane & 15);
        bq[kk][n] = *reinterpret_cast<const bf16x8*>(
            &Bs[slot][half][lrow * 128 + (kb ^ ((lane & 7) << 4))]);
      }
    }
  };

  f32x4 acc[2][2][4][2];
#pragma unroll
  for (int a = 0; a < 2; ++a)
#pragma unroll
    for (int b = 0; b < 2; ++b)
#pragma unroll
      for (int m = 0; m < 4; ++m)
#pragma unroll
        for (int n = 0; n < 2; ++n) acc[a][b][m][n] = (f32x4){0.f, 0.f, 0.f, 0.f};

#define MMQ(QM, QN)                                                            \
  do {                                                                         \
    __builtin_amdgcn_s_setprio(1);                                             \
    _Pragma("unroll") for (int kk = 0; kk < 2; ++kk)                           \
        _Pragma("unroll") for (int m = 0; m < 4; ++m)                          \
            _Pragma("unroll") for (int n = 0; n < 2; ++n)                      \
                acc[QM][QN][m][n] = __builtin_amdgcn_mfma_f32_16x16x32_bf16(   \
                    af[kk][m], bq[kk][n], acc[QM][QN][m][n], 0, 0, 0);         \
    __builtin_amdgcn_s_setprio(0);                                             \
  } while (0)

  const int nk = K / 64;
  const int nj = nk / 2;  // K padded so nk is even

  // prologue: t0 full (A0,A1,B0,B1), then t1.A0, t1.B1 -> vmcnt(4): t0 landed
  STG_A(0, 0, 0); STG_A(0, 1, 0); STG_B(0, 0, 0); STG_B(0, 1, 0);
  if (nk > 1) { STG_A(1, 0, 1); STG_B(1, 1, 1); }
  asm volatile("s_waitcnt vmcnt(4)" ::: "memory");
  BARX;

  for (int j = 0; j < nj; ++j) {
    const int t1 = 2 * j + 1, t2 = 2 * j + 2, t3 = 2 * j + 3;
    const bool more = (t2 < nk);
    // ---- tile t0 = 2j (slot 0) ----
    // ph1 (0,0)
    LDA(0, 0); LDB(0, 0);
    STG_A(t1, 1, 1);
    BARX; LGKM0; MMQ(0, 0); BARX;
    // ph2 (0,1)
    LDB(0, 1);
    STG_B(t1, 0, 1);
    BARX; LGKM0; MMQ(0, 1); BARX;
    // ph3 (1,1)
    LDA(0, 1);
    if (more) STG_A(t2, 0, 0);
    BARX; LGKM0; MMQ(1, 1); BARX;
    // ph4 (1,0)
    LDB(0, 0);
    if (more) STG_B(t2, 1, 0);
    BARX; LGKM0; MMQ(1, 0);
    if (more) { asm volatile("s_waitcnt vmcnt(4)" ::: "memory"); }
    else      { asm volatile("s_waitcnt vmcnt(0)" ::: "memory"); }
    BARX;
    // ---- tile t1 (slot 1) ----
    // ph5 (0,0)
    LDA(1, 0); LDB(1, 0);
    if (more) STG_A(t2, 1, 0);
    BARX; LGKM0; MMQ(0, 0); BARX;
    // ph6 (0,1)
    LDB(1, 1);
    if (more) STG_B(t2, 0, 0);
    BARX; LGKM0; MMQ(0, 1); BARX;
    // ph7 (1,1)
    LDA(1, 1);
    if (more) STG_A(t3, 0, 1);
    BARX; LGKM0; MMQ(1, 1); BARX;
    // ph8 (1,0)
    LDB(1, 0);
    if (more) STG_B(t3, 1, 1);
    BARX; LGKM0; MMQ(1, 0);
    if (more) { asm volatile("s_waitcnt vmcnt(4)" ::: "memory"); }
    BARX;
  }
#undef MMQ

  __hip_bfloat16* C = Call + (long long)e * strideCe;
  const float* eb = ebias + e * strideEb;
  const int m0 = blockIdx.x * 256, n0 = blockIdx.y * 256;
#pragma unroll
  for (int Qm = 0; Qm < 2; ++Qm)
#pragma unroll
    for (int Qn = 0; Qn < 2; ++Qn)
#pragma unroll
      for (int n = 0; n < 2; ++n) {
        const int col = n0 + Qn * 128 + wq_c * 32 + n * 16 + (lane & 15);
        const float s = scale[col];
        const float bb = eb[col];
#pragma unroll
        for (int m = 0; m < 4; ++m) {
          const int rowb = m0 + Qm * 128 + wq_r * 64 + m * 16 + (lane >> 4) * 4;
#pragma unroll
          for (int i = 0; i < 4; ++i) {
            float v = fmaxf(acc[Qm][Qn][m][n][i] * s + bb, 0.f);
            C[(long long)(rowb + i) * N + col] = __float2bfloat16(v);
          }
        }
      }
}

// ---------------- fused combine + BOTH tower MLPs + sigmoid ----------------
// grid: (B/64), block 256 (4 waves, each wave owns 16 rows). h1 read ONCE for both tasks.
__global__ __launch_bounds__(256) void k_tower(
    const __hip_bfloat16* __restrict__ h1, const float* __restrict__ gates,
    const float* __restrict__ Wt1, const float* __restrict__ Wt2,
    const float* __restrict__ bt2, const float* __restrict__ tscale,
    const float* __restrict__ tbias, float* __restrict__ out) {
  __shared__ __align__(16) char Ws[TH_ * 512];  // Ws[h][k] bf16, swizzled; one task at a time
  const int tid = threadIdx.x;
  const int lane = tid & 63, wv = tid >> 6;

  const int row = blockIdx.x * 64 + wv * 16 + (lane & 15);
  const int g4 = lane >> 4;

  float gt0[8], gt1[8];
  {
    const float* gp0 = gates + (long long)row * E_;
    const float* gp1 = gates + ((long long)B_ + row) * E_;
#pragma unroll
    for (int j = 0; j < 8; ++j) { gt0[j] = gp0[j]; gt1[j] = gp1[j]; }
  }

  float fa0[8][8], fa1[8][8];
#pragma unroll
  for (int c = 0; c < 8; ++c)
#pragma unroll
    for (int j = 0; j < 8; ++j) { fa0[c][j] = 0.f; fa1[c][j] = 0.f; }

#pragma unroll
  for (int ee = 0; ee < 8; ++ee) {
    const char* hp = reinterpret_cast<const char*>(h1) +
                     (((long long)ee * B_ + row) * H1_ + g4 * 8) * 2;
    float ga = gt0[ee], gb = gt1[ee];
#pragma unroll
    for (int c = 0; c < 8; ++c) {
      bf16x8 hv = *reinterpret_cast<const bf16x8*>(hp + c * 64);
#pragma unroll
      for (int j = 0; j < 8; ++j) {
        float v = (float)hv[j];
        fa0[c][j] += ga * v;
        fa1[c][j] += gb * v;
      }
    }
  }
  bf16x8 af0[8], af1[8];
#pragma unroll
  for (int c = 0; c < 8; ++c)
#pragma unroll
    for (int j = 0; j < 8; ++j) {
      af0[c][j] = (__bf16)fa0[c][j];
      af1[c][j] = (__bf16)fa1[c][j];
    }

#pragma unroll
  for (int t = 0; t < T_; ++t) {
    if (t) __syncthreads();
    for (int it = 0; it < 16; ++it) {
      int idx = it * 256 + tid;
      int h = idx & 127, kc = idx >> 7;
      bf16x8 v;
#pragma unroll
      for (int j = 0; j < 8; ++j)
        v[j] = (__bf16)Wt1[((long long)t * H1_ + kc * 8 + j) * TH_ + h];
      int byt = h * 512 + ((kc * 16) ^ ((h & 7) << 4));
      *reinterpret_cast<bf16x8*>(Ws + byt) = v;
    }
    __syncthreads();

    f32x4 acc[8];
#pragma unroll
    for (int n = 0; n < 8; ++n) acc[n] = (f32x4){0.f, 0.f, 0.f, 0.f};
#pragma unroll
    for (int c = 0; c < 8; ++c) {
      int kb = c * 64 + g4 * 16;
#pragma unroll
      for (int n = 0; n < 8; ++n) {
        int hrow = n * 16 + (lane & 15);
        bf16x8 bv = *reinterpret_cast<const bf16x8*>(Ws + hrow * 512 + (kb ^ ((hrow & 7) << 4)));
        acc[n] = __builtin_amdgcn_mfma_f32_16x16x32_bf16(t ? af1[c] : af0[c], bv, acc[n], 0, 0, 0);
      }
    }

    float part[4] = {0.f, 0.f, 0.f, 0.f};
#pragma unroll
    for (int n = 0; n < 8; ++n) {
      int col = n * 16 + (lane & 15);
      float s = tscale[t * TH_ + col], bb = tbias[t * TH_ + col], w2 = Wt2[t * TH_ + col];
#pragma unroll
      for (int i = 0; i < 4; ++i)
        part[i] += fmaxf(acc[n][i] * s + bb, 0.f) * w2;
    }
#pragma unroll
    for (int o = 1; o < 16; o <<= 1) {
#pragma unroll
      for (int i = 0; i < 4; ++i) part[i] += __shfl_xor(part[i], o);
    }
    if ((lane & 15) == 0) {
      int rbase = blockIdx.x * 64 + wv * 16 + g4 * 4;
      float b2 = bt2[t];
#pragma unroll
      for (int i = 0; i < 4; ++i) {
        float z = part[i] + b2;
        out[(long long)t * B_ + rbase + i] = 1.f / (1.f + __expf(-z));
      }
    }
  }
}

extern "C" void kernel_launch(void* const* d_in, const int* in_sizes, int n_in,
                              void* d_out, int out_size, void* d_ws, size_t ws_size,
                              hipStream_t stream) {
  const int*   cat = (const int*)d_in[0];
  const float* num = (const float*)d_in[1];
  const float* emb = (const float*)d_in[3];
  const float* W0  = (const float*)d_in[4];
  const float* b0  = (const float*)d_in[5];
  const float* g0  = (const float*)d_in[6];
  const float* be0 = (const float*)d_in[7];
  const float* m0  = (const float*)d_in[8];
  const float* v0  = (const float*)d_in[9];
  const float* W1  = (const float*)d_in[10];
  const float* b1  = (const float*)d_in[11];
  const float* g1  = (const float*)d_in[12];
  const float* be1 = (const float*)d_in[13];
  const float* m1  = (const float*)d_in[14];
  const float* v1  = (const float*)d_in[15];
  const float* Wg  = (const float*)d_in[16];
  const float* bg  = (const float*)d_in[17];
  const float* Wt1 = (const float*)d_in[18];
  const float* bt1 = (const float*)d_in[19];
  const float* tg  = (const float*)d_in[20];
  const float* tb  = (const float*)d_in[21];
  const float* tm  = (const float*)d_in[22];
  const float* tv  = (const float*)d_in[23];
  const float* Wt2 = (const float*)d_in[24];
  const float* bt2 = (const float*)d_in[25];
  float* out = (float*)d_out;

  char* ws = (char*)d_ws;
  if (ws_size < 230719488ULL) return;

  __hip_bfloat16* x_bf = (__hip_bfloat16*)(ws + 0ULL);            // 16384*640*2 = 20971520
  __hip_bfloat16* W0p  = (__hip_bfloat16*)(ws + 20971520ULL);     // 8*512*640*2 = 5242880
  __hip_bfloat16* W1p  = (__hip_bfloat16*)(ws + 26214400ULL);     // 8*256*512*2 = 2097152
  float* gates   = (float*)(ws + 28311552ULL);                    // 2*16384*8*4 = 1048576
  float* scale0  = (float*)(ws + 29360128ULL);
  float* ebias0  = (float*)(ws + 29362176ULL);
  float* scale1  = (float*)(ws + 29378560ULL);
  float* ebias1  = (float*)(ws + 29379584ULL);
  float* tscale  = (float*)(ws + 29387776ULL);
  float* tbias   = (float*)(ws + 29388800ULL);
  __hip_bfloat16* h0 = (__hip_bfloat16*)(ws + 29392896ULL);       // 8*16384*512*2 = 134217728
  __hip_bfloat16* h1 = (__hip_bfloat16*)(ws + 163610624ULL);      // 8*16384*256*2 = 67108864

  // weight prep + BN folding
  k_wprep<<<dim3(K0P / 64, H0_ / 64, E_), 256, 0, stream>>>(W0, W0p, D0_, H0_, K0P);
  k_wprep<<<dim3(H0_ / 64, H1_ / 64, E_), 256, 0, stream>>>(W1, W1p, H0_, H1_, H0_);
  k_prep_small<<<16, 256, 0, stream>>>(b0, g0, be0, m0, v0, b1, g1, be1, m1, v1,
                                       bt1, tg, tb, tm, tv,
                                       scale0, ebias0, scale1, ebias1, tscale, tbias);
  // embedding + concat
  k_embed<<<B_, 256, 0, stream>>>(cat, num, emb, x_bf);
  // gates
  k_gates<<<B_ * 16 / 256, 256, 0, stream>>>(x_bf, Wg, bg, gates);
  // layer 0: [B,640] x [E,512,640]^T -> h0 [E,B,512]
  k_gemm<<<dim3(B_ / 256, H0_ / 256, E_), 512, 0, stream>>>(
      x_bf, 0LL, K0P, W0p, (long long)H0_ * K0P, K0P,
      h0, (long long)B_ * H0_, H0_, scale0, ebias0, H0_, K0P);
  // layer 1: h0 [E,B,512] x [E,256,512]^T -> h1 [E,B,256]
  k_gemm<<<dim3(B_ / 256, H1_ / 256, E_), 512, 0, stream>>>(
      h0, (long long)B_ * H0_, H0_, W1p, (long long)H1_ * H0_, H0_,
      h1, (long long)B_ * H1_, H1_, scale1, ebias1, H1_, H0_);
  // combine + BOTH towers + sigmoid
  k_tower<<<dim3(B_ / 64), 256, 0, stream>>>(h1, gates, Wt1, Wt2, bt2,
                                             tscale, tbias, out);
}

// Round 6
// 257.603 us; speedup vs baseline: 1.2361x; 1.1449x over previous
//
#include <hip/hip_runtime.h>
#include <hip/hip_bf16.h>

#define B_ 16384
#define NF_ 16
#define VOCAB_ 100000
#define ED_ 32
#define NNUM_ 13
#define E_ 8
#define T_ 2
#define H0_ 512
#define H1_ 256
#define TH_ 128
#define D0_ 525
#define K0P 640   // padded K for layer 0 (multiple of 128 -> even # of 64-K-tiles)

typedef __bf16 bf16x8 __attribute__((ext_vector_type(8)));
typedef float  f32x4  __attribute__((ext_vector_type(4)));

typedef __attribute__((address_space(3))) void lds_void;
typedef __attribute__((address_space(1))) const void gbl_void;

__device__ __forceinline__ void load_lds16f(const void* g, void* l) {
  __builtin_amdgcn_global_load_lds((gbl_void*)g, (lds_void*)l, 16, 0, 0);
}

#define BARX                                        \
  do {                                              \
    asm volatile("" ::: "memory");                  \
    __builtin_amdgcn_s_barrier();                   \
    __builtin_amdgcn_sched_barrier(0);              \
    asm volatile("" ::: "memory");                  \
  } while (0)
#define LGKM0                                       \
  do {                                              \
    asm volatile("s_waitcnt lgkmcnt(0)" ::: "memory"); \
    __builtin_amdgcn_sched_barrier(0);              \
  } while (0)

// ---------------- embedding + concat + pad + cast ----------------
__global__ __launch_bounds__(256) void k_embed(const int* __restrict__ cat,
                                               const float* __restrict__ num,
                                               const float* __restrict__ emb,
                                               __hip_bfloat16* __restrict__ x) {
  int b = blockIdx.x;
  int t = threadIdx.x;
  const int* crow = cat + b * NF_;
#pragma unroll
  for (int i = 0; i < 3; ++i) {
    int d = t + i * 256;  // 0..767
    if (d >= K0P) continue;
    float v;
    if (d < 512) {
      int f = d >> 5, c = d & 31;
      v = emb[((long long)(f * VOCAB_ + crow[f])) * ED_ + c];
    } else if (d < D0_) {
      v = num[b * NNUM_ + (d - 512)];
    } else {
      v = 0.f;
    }
    x[(long long)b * K0P + d] = __float2bfloat16(v);
  }
}

// ---------------- weight transpose + pad + cast: W[E][K][N] f32 -> Wp[E][N][KP] bf16 ----------------
__global__ __launch_bounds__(256) void k_wprep(const float* __restrict__ W,
                                               __hip_bfloat16* __restrict__ Wp,
                                               int K, int N, int KP) {
  __shared__ float tile[64][65];
  int k0 = blockIdx.x * 64, n0 = blockIdx.y * 64, e = blockIdx.z;
  int tx = threadIdx.x & 63, ty = threadIdx.x >> 6;
  for (int r = ty; r < 64; r += 4) {
    int k = k0 + r;
    tile[r][tx] = (k < K) ? W[((long long)e * K + k) * N + n0 + tx] : 0.f;
  }
  __syncthreads();
  for (int r = ty; r < 64; r += 4) {
    int n = n0 + r;
    Wp[((long long)e * N + n) * KP + k0 + tx] = __float2bfloat16(tile[tx][r]);
  }
}

// ---------------- BN param folding ----------------
__global__ void k_prep_small(const float* b0, const float* g0, const float* be0,
                             const float* m0, const float* v0,
                             const float* b1, const float* g1, const float* be1,
                             const float* m1, const float* v1,
                             const float* bt1, const float* tg, const float* tb,
                             const float* tm, const float* tv,
                             float* scale0, float* ebias0, float* scale1, float* ebias1,
                             float* tscale, float* tbias) {
  int i = blockIdx.x * 256 + threadIdx.x;
  if (i < H0_) scale0[i] = g0[i] * rsqrtf(v0[i] + 1e-5f);
  if (i < H1_) scale1[i] = g1[i] * rsqrtf(v1[i] + 1e-5f);
  if (i < T_ * TH_) {
    float s = tg[i] * rsqrtf(tv[i] + 1e-5f);
    tscale[i] = s;
    tbias[i] = (bt1[i] - tm[i]) * s + tb[i];
  }
  if (i < E_ * H0_) {
    int n = i & (H0_ - 1);
    float s = g0[n] * rsqrtf(v0[n] + 1e-5f);
    ebias0[i] = (b0[i] - m0[n]) * s + be0[n];
  }
  if (i < E_ * H1_) {
    int n = i & (H1_ - 1);
    float s = g1[n] * rsqrtf(v1[n] + 1e-5f);
    ebias1[i] = (b1[i] - m1[n]) * s + be1[n];
  }
}

// ---------------- gate logits + softmax over 8 experts ----------------
__global__ __launch_bounds__(256) void k_gates(const __hip_bfloat16* __restrict__ x,
                                               const float* __restrict__ Wg,
                                               const float* __restrict__ bg,
                                               float* __restrict__ gates) {
  int gidx = blockIdx.x * 256 + threadIdx.x;
  int b = gidx >> 4, te = gidx & 15;
  int t = te >> 3, e = te & 7;
  const __hip_bfloat16* xr = x + (long long)b * K0P;
  const float* wg = Wg + ((long long)t * D0_) * E_ + e;
  float acc = bg[t * E_ + e];
  int k = 0;
  for (; k + 8 <= D0_; k += 8) {
    bf16x8 xv = *reinterpret_cast<const bf16x8*>(xr + k);
#pragma unroll
    for (int j = 0; j < 8; ++j)
      acc += (float)xv[j] * wg[(long long)(k + j) * E_];
  }
  for (; k < D0_; ++k) acc += __bfloat162float(xr[k]) * wg[(long long)k * E_];
  float mx = acc;
#pragma unroll
  for (int o = 1; o < 8; o <<= 1) mx = fmaxf(mx, __shfl_xor(mx, o));
  float p = __expf(acc - mx);
  float s = p;
#pragma unroll
  for (int o = 1; o < 8; o <<= 1) s += __shfl_xor(s, o);
  gates[((long long)t * B_ + b) * E_ + e] = p / s;
}

// ---------------- grouped GEMM + BN + ReLU -> bf16, 8-phase schedule ----------------
__global__ __launch_bounds__(512, 2) void k_gemm(
    const __hip_bfloat16* __restrict__ Aall, long long strideAe, int lda,
    const __hip_bfloat16* __restrict__ Ball, long long strideBe, int ldb,
    __hip_bfloat16* __restrict__ Call, long long strideCe, int N,
    const float* __restrict__ scale, const float* __restrict__ ebias, int strideEb,
    int K) {
  __shared__ __align__(16) char As[2][2][16384];  // [slot][half]: 128 rows x 128 B
  __shared__ __align__(16) char Bs[2][2][16384];

  const int e = blockIdx.z;
  const char* A = reinterpret_cast<const char*>(Aall + (long long)e * strideAe +
                                                (long long)blockIdx.x * 256 * lda);
  const char* Bw = reinterpret_cast<const char*>(Ball + (long long)e * strideBe +
                                                 (long long)blockIdx.y * 256 * ldb);
  const int ldab = lda * 2, ldbb = ldb * 2;

  const int tid = threadIdx.x;
  const int lane = tid & 63;
  const int wid = tid >> 6;
  const int wq_r = wid >> 2, wq_c = wid & 3;  // within-quadrant: 2Mx4N waves

  const int srow = tid >> 3;                          // 0..63
  const int swz = ((tid & 7) << 4) ^ ((srow & 7) << 4);

  auto STG_A = [&](int kt, int half, int slot) {
#pragma unroll
    for (int j = 0; j < 2; ++j) {
      const int lrow = srow + j * 64;
      load_lds16f(A + (long long)(half * 128 + lrow) * ldab + kt * 128 + swz,
                  &As[slot][half][j * 8192 + tid * 16]);
    }
  };
  auto STG_B = [&](int kt, int half, int slot) {
#pragma unroll
    for (int j = 0; j < 2; ++j) {
      const int lrow = srow + j * 64;
      load_lds16f(Bw + (long long)(half * 128 + lrow) * ldbb + kt * 128 + swz,
                  &Bs[slot][half][j * 8192 + tid * 16]);
    }
  };

  bf16x8 af[2][4], bq[2][2];
  auto LDA = [&](int slot, int half) {
#pragma unroll
    for (int kk = 0; kk < 2; ++kk) {
      const int kb = kk * 64 + (lane >> 4) * 16;
#pragma unroll
      for (int m = 0; m < 4; ++m) {
        const int lrow = wq_r * 64 + m * 16 + (lane & 15);
        af[kk][m] = *reinterpret_cast<const bf16x8*>(
            &As[slot][half][lrow * 128 + (kb ^ ((lane & 7) << 4))]);
      }
    }
  };
  auto LDB = [&](int slot, int half) {
#pragma unroll
    for (int kk = 0; kk < 2; ++kk) {
      const int kb = kk * 64 + (lane >> 4) * 16;
#pragma unroll
      for (int n = 0; n < 2; ++n) {
        const int lrow = wq_c * 32 + n * 16 + (lane & 15);
        bq[kk][n] = *reinterpret_cast<const bf16x8*>(
            &Bs[slot][half][lrow * 128 + (kb ^ ((lane & 7) << 4))]);
      }
    }
  };

  f32x4 acc[2][2][4][2];
#pragma unroll
  for (int a = 0; a < 2; ++a)
#pragma unroll
    for (int b = 0; b < 2; ++b)
#pragma unroll
      for (int m = 0; m < 4; ++m)
#pragma unroll
        for (int n = 0; n < 2; ++n) acc[a][b][m][n] = (f32x4){0.f, 0.f, 0.f, 0.f};

#define MMQ(QM, QN)                                                            \
  do {                                                                         \
    __builtin_amdgcn_s_setprio(1);                                             \
    _Pragma("unroll") for (int kk = 0; kk < 2; ++kk)                           \
        _Pragma("unroll") for (int m = 0; m < 4; ++m)                          \
            _Pragma("unroll") for (int n = 0; n < 2; ++n)                      \
                acc[QM][QN][m][n] = __builtin_amdgcn_mfma_f32_16x16x32_bf16(   \
                    af[kk][m], bq[kk][n], acc[QM][QN][m][n], 0, 0, 0);         \
    __builtin_amdgcn_s_setprio(0);                                             \
  } while (0)

  const int nk = K / 64;
  const int nj = nk / 2;  // K padded so nk is even

  // prologue: t0 full, then t1.A0, t1.B1 -> vmcnt(4): t0 landed
  STG_A(0, 0, 0); STG_A(0, 1, 0); STG_B(0, 0, 0); STG_B(0, 1, 0);
  if (nk > 1) { STG_A(1, 0, 1); STG_B(1, 1, 1); }
  asm volatile("s_waitcnt vmcnt(4)" ::: "memory");
  BARX;

  for (int j = 0; j < nj; ++j) {
    const int t1 = 2 * j + 1, t2 = 2 * j + 2, t3 = 2 * j + 3;
    const bool more = (t2 < nk);
    // ---- tile t0 = 2j (slot 0) ----
    LDA(0, 0); LDB(0, 0);
    STG_A(t1, 1, 1);
    BARX; LGKM0; MMQ(0, 0); BARX;
    LDB(0, 1);
    STG_B(t1, 0, 1);
    BARX; LGKM0; MMQ(0, 1); BARX;
    LDA(0, 1);
    if (more) STG_A(t2, 0, 0);
    BARX; LGKM0; MMQ(1, 1); BARX;
    LDB(0, 0);
    if (more) STG_B(t2, 1, 0);
    BARX; LGKM0; MMQ(1, 0);
    if (more) { asm volatile("s_waitcnt vmcnt(4)" ::: "memory"); }
    else      { asm volatile("s_waitcnt vmcnt(0)" ::: "memory"); }
    BARX;
    // ---- tile t1 (slot 1) ----
    LDA(1, 0); LDB(1, 0);
    if (more) STG_A(t2, 1, 0);
    BARX; LGKM0; MMQ(0, 0); BARX;
    LDB(1, 1);
    if (more) STG_B(t2, 0, 0);
    BARX; LGKM0; MMQ(0, 1); BARX;
    LDA(1, 1);
    if (more) STG_A(t3, 0, 1);
    BARX; LGKM0; MMQ(1, 1); BARX;
    LDB(1, 0);
    if (more) STG_B(t3, 1, 1);
    BARX; LGKM0; MMQ(1, 0);
    if (more) { asm volatile("s_waitcnt vmcnt(4)" ::: "memory"); }
    BARX;
  }
#undef MMQ

  __hip_bfloat16* C = Call + (long long)e * strideCe;
  const float* eb = ebias + e * strideEb;
  const int m0 = blockIdx.x * 256, n0 = blockIdx.y * 256;
#pragma unroll
  for (int Qm = 0; Qm < 2; ++Qm)
#pragma unroll
    for (int Qn = 0; Qn < 2; ++Qn)
#pragma unroll
      for (int n = 0; n < 2; ++n) {
        const int col = n0 + Qn * 128 + wq_c * 32 + n * 16 + (lane & 15);
        const float s = scale[col];
        const float bb = eb[col];
#pragma unroll
        for (int m = 0; m < 4; ++m) {
          const int rowb = m0 + Qm * 128 + wq_r * 64 + m * 16 + (lane >> 4) * 4;
#pragma unroll
          for (int i = 0; i < 4; ++i) {
            float v = fmaxf(acc[Qm][Qn][m][n][i] * s + bb, 0.f);
            C[(long long)(rowb + i) * N + col] = __float2bfloat16(v);
          }
        }
      }
}

// ---------------- gate-weighted combine: fea[t][b][:] = sum_e g[t][b][e]*h1[e][b][:] ----------------
// grid 2048 x 256: one 16B chunk (8 bf16 of H1) per thread, both tasks in one h1 pass.
__global__ __launch_bounds__(256) void k_combine(const __hip_bfloat16* __restrict__ h1,
                                                 const float* __restrict__ gates,
                                                 __hip_bfloat16* __restrict__ fea) {
  const int idx = blockIdx.x * 256 + threadIdx.x;  // 0 .. B*H1/8-1
  const int b = idx >> 5, c = idx & 31;
  const f32x4* gp0 = reinterpret_cast<const f32x4*>(gates + (long long)b * E_);
  const f32x4* gp1 = reinterpret_cast<const f32x4*>(gates + ((long long)B_ + b) * E_);
  const f32x4 g0lo = gp0[0], g0hi = gp0[1];
  const f32x4 g1lo = gp1[0], g1hi = gp1[1];

  float a0[8], a1[8];
#pragma unroll
  for (int j = 0; j < 8; ++j) { a0[j] = 0.f; a1[j] = 0.f; }

#pragma unroll
  for (int ee = 0; ee < 8; ++ee) {
    bf16x8 hv = *reinterpret_cast<const bf16x8*>(
        h1 + ((long long)ee * B_ + b) * H1_ + c * 8);
    const float ga = (ee < 4) ? g0lo[ee & 3] : g0hi[ee & 3];
    const float gb = (ee < 4) ? g1lo[ee & 3] : g1hi[ee & 3];
#pragma unroll
    for (int j = 0; j < 8; ++j) {
      float v = (float)hv[j];
      a0[j] += ga * v;
      a1[j] += gb * v;
    }
  }
  bf16x8 o0, o1;
#pragma unroll
  for (int j = 0; j < 8; ++j) { o0[j] = (__bf16)a0[j]; o1[j] = (__bf16)a1[j]; }
  *reinterpret_cast<bf16x8*>(fea + (long long)b * H1_ + c * 8) = o0;
  *reinterpret_cast<bf16x8*>(fea + ((long long)B_ + b) * H1_ + c * 8) = o1;
}

// ---------------- per-task tower MLP + sigmoid ----------------
// grid (B/64, T), block 256 (4 waves, each wave owns 16 rows); A-frags direct from fea.
__global__ __launch_bounds__(256) void k_tower2(
    const __hip_bfloat16* __restrict__ fea, const float* __restrict__ Wt1,
    const float* __restrict__ Wt2, const float* __restrict__ bt2,
    const float* __restrict__ tscale, const float* __restrict__ tbias,
    float* __restrict__ out) {
  __shared__ __align__(16) char Ws[TH_ * 512];  // Ws[h][k] bf16, swizzled
  const int t = blockIdx.y;
  const int tid = threadIdx.x;
  const int lane = tid & 63, wv = tid >> 6;

  const int row = blockIdx.x * 64 + wv * 16 + (lane & 15);
  const int g4 = lane >> 4;

  // stage Wt1[t][k][h] f32 -> Ws[h][k] bf16 (swizzled); coalesced over h
  for (int it = 0; it < 16; ++it) {
    int idx = it * 256 + tid;
    int h = idx & 127, kc = idx >> 7;
    bf16x8 v;
#pragma unroll
    for (int j = 0; j < 8; ++j)
      v[j] = (__bf16)Wt1[((long long)t * H1_ + kc * 8 + j) * TH_ + h];
    int byt = h * 512 + ((kc * 16) ^ ((h & 7) << 4));
    *reinterpret_cast<bf16x8*>(Ws + byt) = v;
  }

  // A-fragments direct from fea: af[c][j] = fea[t][row][c*32 + g4*8 + j]
  bf16x8 af[8];
  {
    const __hip_bfloat16* fp = fea + ((long long)t * B_ + row) * H1_ + g4 * 8;
#pragma unroll
    for (int c = 0; c < 8; ++c)
      af[c] = *reinterpret_cast<const bf16x8*>(fp + c * 32);
  }
  __syncthreads();

  f32x4 acc[8];
#pragma unroll
  for (int n = 0; n < 8; ++n) acc[n] = (f32x4){0.f, 0.f, 0.f, 0.f};
#pragma unroll
  for (int c = 0; c < 8; ++c) {
    int kb = c * 64 + g4 * 16;
#pragma unroll
    for (int n = 0; n < 8; ++n) {
      int hrow = n * 16 + (lane & 15);
      bf16x8 bv = *reinterpret_cast<const bf16x8*>(Ws + hrow * 512 + (kb ^ ((hrow & 7) << 4)));
      acc[n] = __builtin_amdgcn_mfma_f32_16x16x32_bf16(af[c], bv, acc[n], 0, 0, 0);
    }
  }

  float part[4] = {0.f, 0.f, 0.f, 0.f};
#pragma unroll
  for (int n = 0; n < 8; ++n) {
    int col = n * 16 + (lane & 15);
    float s = tscale[t * TH_ + col], bb = tbias[t * TH_ + col], w2 = Wt2[t * TH_ + col];
#pragma unroll
    for (int i = 0; i < 4; ++i)
      part[i] += fmaxf(acc[n][i] * s + bb, 0.f) * w2;
  }
#pragma unroll
  for (int o = 1; o < 16; o <<= 1) {
#pragma unroll
    for (int i = 0; i < 4; ++i) part[i] += __shfl_xor(part[i], o);
  }
  if ((lane & 15) == 0) {
    int rbase = blockIdx.x * 64 + wv * 16 + g4 * 4;
    float b2 = bt2[t];
#pragma unroll
    for (int i = 0; i < 4; ++i) {
      float z = part[i] + b2;
      out[(long long)t * B_ + rbase + i] = 1.f / (1.f + __expf(-z));
    }
  }
}

extern "C" void kernel_launch(void* const* d_in, const int* in_sizes, int n_in,
                              void* d_out, int out_size, void* d_ws, size_t ws_size,
                              hipStream_t stream) {
  const int*   cat = (const int*)d_in[0];
  const float* num = (const float*)d_in[1];
  const float* emb = (const float*)d_in[3];
  const float* W0  = (const float*)d_in[4];
  const float* b0  = (const float*)d_in[5];
  const float* g0  = (const float*)d_in[6];
  const float* be0 = (const float*)d_in[7];
  const float* m0  = (const float*)d_in[8];
  const float* v0  = (const float*)d_in[9];
  const float* W1  = (const float*)d_in[10];
  const float* b1  = (const float*)d_in[11];
  const float* g1  = (const float*)d_in[12];
  const float* be1 = (const float*)d_in[13];
  const float* m1  = (const float*)d_in[14];
  const float* v1  = (const float*)d_in[15];
  const float* Wg  = (const float*)d_in[16];
  const float* bg  = (const float*)d_in[17];
  const float* Wt1 = (const float*)d_in[18];
  const float* bt1 = (const float*)d_in[19];
  const float* tg  = (const float*)d_in[20];
  const float* tb  = (const float*)d_in[21];
  const float* tm  = (const float*)d_in[22];
  const float* tv  = (const float*)d_in[23];
  const float* Wt2 = (const float*)d_in[24];
  const float* bt2 = (const float*)d_in[25];
  float* out = (float*)d_out;

  char* ws = (char*)d_ws;
  if (ws_size < 247496704ULL) return;

  __hip_bfloat16* x_bf = (__hip_bfloat16*)(ws + 0ULL);            // 16384*640*2 = 20971520
  __hip_bfloat16* W0p  = (__hip_bfloat16*)(ws + 20971520ULL);     // 8*512*640*2 = 5242880
  __hip_bfloat16* W1p  = (__hip_bfloat16*)(ws + 26214400ULL);     // 8*256*512*2 = 2097152
  float* gates   = (float*)(ws + 28311552ULL);                    // 2*16384*8*4 = 1048576
  float* scale0  = (float*)(ws + 29360128ULL);
  float* ebias0  = (float*)(ws + 29362176ULL);
  float* scale1  = (float*)(ws + 29378560ULL);
  float* ebias1  = (float*)(ws + 29379584ULL);
  float* tscale  = (float*)(ws + 29387776ULL);
  float* tbias   = (float*)(ws + 29388800ULL);
  __hip_bfloat16* h0  = (__hip_bfloat16*)(ws + 29392896ULL);      // 8*16384*512*2 = 134217728
  __hip_bfloat16* h1  = (__hip_bfloat16*)(ws + 163610624ULL);     // 8*16384*256*2 = 67108864
  __hip_bfloat16* fea = (__hip_bfloat16*)(ws + 230719488ULL);     // 2*16384*256*2 = 16777216

  // weight prep + BN folding
  k_wprep<<<dim3(K0P / 64, H0_ / 64, E_), 256, 0, stream>>>(W0, W0p, D0_, H0_, K0P);
  k_wprep<<<dim3(H0_ / 64, H1_ / 64, E_), 256, 0, stream>>>(W1, W1p, H0_, H1_, H0_);
  k_prep_small<<<16, 256, 0, stream>>>(b0, g0, be0, m0, v0, b1, g1, be1, m1, v1,
                                       bt1, tg, tb, tm, tv,
                                       scale0, ebias0, scale1, ebias1, tscale, tbias);
  // embedding + concat
  k_embed<<<B_, 256, 0, stream>>>(cat, num, emb, x_bf);
  // gates
  k_gates<<<B_ * 16 / 256, 256, 0, stream>>>(x_bf, Wg, bg, gates);
  // layer 0: [B,640] x [E,512,640]^T -> h0 [E,B,512]
  k_gemm<<<dim3(B_ / 256, H0_ / 256, E_), 512, 0, stream>>>(
      x_bf, 0LL, K0P, W0p, (long long)H0_ * K0P, K0P,
      h0, (long long)B_ * H0_, H0_, scale0, ebias0, H0_, K0P);
  // layer 1: h0 [E,B,512] x [E,256,512]^T -> h1 [E,B,256]
  k_gemm<<<dim3(B_ / 256, H1_ / 256, E_), 512, 0, stream>>>(
      h0, (long long)B_ * H0_, H0_, W1p, (long long)H1_ * H0_, H0_,
      h1, (long long)B_ * H1_, H1_, scale1, ebias1, H1_, H0_);
  // gate-weighted combine (both tasks, one h1 pass)
  k_combine<<<B_ * H1_ / 8 / 256, 256, 0, stream>>>(h1, gates, fea);
  // per-task tower MLP + sigmoid
  k_tower2<<<dim3(B_ / 64, T_), 256, 0, stream>>>(fea, Wt1, Wt2, bt2,
                                                  tscale, tbias, out);
}